// Round 11
// baseline (291.316 us; speedup 1.0000x reference)
//
#include <hip/hip_runtime.h>
#include <hip/hip_fp16.h>

// B=32768, D_IN=256, H1=256, D_OUT=64, E=32, T=16
#define NTHR 256            // 4 waves, 1 wave/SIMD (512-reg budget)
#define BM   128
#define NBLK 256
#define NEXP 32

using f16x8 = __attribute__((ext_vector_type(8))) _Float16;
using f16x4 = __attribute__((ext_vector_type(4))) _Float16;
using f32x4 = __attribute__((ext_vector_type(4))) float;
using u32x4 = __attribute__((ext_vector_type(4))) unsigned int;
using u32x2 = __attribute__((ext_vector_type(2))) unsigned int;

// ---- per-expert stream (bytes): stride 182272 ----  (layout UNCHANGED from R8)
//   [0)      8 x 16KB W1 fragment tiles (kc 0..7)
//   [131072) 24KB WVplus wn0 frags
//   [155648) 24KB WVplus wn1 frags
//   [180224) 1KB b1 (256 f32)
//   [181248) 1KB b2v (80 f32 used)
static constexpr size_t ESTRIDE_B = 182272;   // = 91136 halves

__device__ __forceinline__ unsigned short f2h(float x){
  _Float16 h = (_Float16)x; return __builtin_bit_cast(unsigned short, h);
}

typedef __attribute__((address_space(3))) void lds_void;
typedef const __attribute__((address_space(1))) void glb_void;
__device__ __forceinline__ void gll16(const void* g, void* l){
  __builtin_amdgcn_global_load_lds((glb_void*)g, (lds_void*)l, 16, 0, 0);
}

#define VMW(N)  asm volatile("s_waitcnt vmcnt(" #N ")" ::: "memory")
#define LGKM0   asm volatile("s_waitcnt lgkmcnt(0)" ::: "memory")
#define SB      __builtin_amdgcn_sched_barrier(0)
#define BARRIER do { SB; __builtin_amdgcn_s_barrier(); SB; } while(0)

// ---------------------------------------------------------------------------
// prep 1: W1 [E][256][256] f32 -> per-(e,kc) 16KB fragment tile. (unchanged)
// ---------------------------------------------------------------------------
__global__ __launch_bounds__(256) void prep_w1frag(const float* __restrict__ W1,
                                                   unsigned short* __restrict__ strm){
  const int e = blockIdx.x >> 3, kc = blockIdx.x & 7;
  const float* se = W1 + (size_t)e*65536 + (size_t)kc*32*256;
  unsigned short* de = strm + (size_t)e*91136 + kc*8192;
  for (int fl = threadIdx.x; fl < 1024; fl += 256){
    const int ct = fl >> 6, l = fl & 63;
    const float* s0 = se + (size_t)((l>>4)*8)*256 + ct*16 + (l&15);
    union { unsigned short s[8]; u32x4 v; } h8;
    #pragma unroll
    for (int j = 0; j < 8; j++) h8.s[j] = f2h(s0[(size_t)j*256]);
    *reinterpret_cast<u32x4*>(&de[fl*8]) = h8.v;
  }
}

// ---------------------------------------------------------------------------
// prep 2: WVplus fragments + b1 + b2v into stream. (unchanged)
// ---------------------------------------------------------------------------
__global__ __launch_bounds__(256) void prep_wvp(
    const float* __restrict__ W2, const float* __restrict__ V,
    const float* __restrict__ Km, const float* __restrict__ Q,
    const float* __restrict__ b1, const float* __restrict__ b2,
    unsigned short* __restrict__ strm, float* __restrict__ out)
{
  const int e = blockIdx.x >> 3, oct = blockIdx.x & 7;
  const int t = threadIdx.x;
  __shared__ float lv[64*64];
  __shared__ float ktlT[64*16];
  __shared__ float lw2[32*64];

  for (int i = t; i < 1024; i += 256)
    *reinterpret_cast<float4*>(&lv[i*4]) = *reinterpret_cast<const float4*>(V + (size_t)e*4096 + i*4);
  for (int i = t; i < 512; i += 256)
    *reinterpret_cast<float4*>(&lw2[i*4]) = *reinterpret_cast<const float4*>(W2 + (size_t)e*16384 + (size_t)oct*2048 + i*4);
  #pragma unroll
  for (int pass = 0; pass < 4; pass++){
    const int id = t + pass*256;
    const int tt = id >> 6, i = id & 63;
    const float4* Kr = reinterpret_cast<const float4*>(Km + (size_t)(e*64 + i)*64);
    const float4* qr = reinterpret_cast<const float4*>(Q + tt*64);
    float s = 0.f;
    #pragma unroll
    for (int j = 0; j < 16; j++){ float4 a = Kr[j], b = qr[j]; s += a.x*b.x+a.y*b.y+a.z*b.z+a.w*b.w; }
    ktlT[i*16 + tt] = s;
  }
  __syncthreads();

  const int k2 = oct*32 + (t >> 3);
  const int cb = t & 7;
  const int c0 = cb*12;
  const float* w2r = &lw2[(t>>3)*64];
  const float* gp[3]; int gs[3]; bool gv[3];
  #pragma unroll
  for (int q = 0; q < 3; q++){
    const int cg = c0 + q*4;
    gv[q] = (cg < 80);
    if (cg < 64){ gp[q] = &lv[cg];        gs[q] = 64; }
    else        { gp[q] = &ktlT[cg - 64]; gs[q] = 16; }
  }
  float pv[12];
  #pragma unroll
  for (int n = 0; n < 12; n++) pv[n] = 0.f;
  for (int i = 0; i < 64; i++){
    const float w = w2r[i];
    #pragma unroll
    for (int q = 0; q < 3; q++){
      if (gv[q]){
        const float4 vq = *reinterpret_cast<const float4*>(gp[q] + i*gs[q]);
        pv[q*4+0] += w*vq.x; pv[q*4+1] += w*vq.y; pv[q*4+2] += w*vq.z; pv[q*4+3] += w*vq.w;
      }
    }
  }
  const int wn_ = k2 >> 7, fn = (k2 >> 4) & 7, fnp = fn >> 1, half = fn & 1;
  const int g2 = (k2 >> 2) & 3, jj = k2 & 3;
  unsigned short* fb = strm + (size_t)e*91136 + (wn_ ? 77824 : 65536);
  #pragma unroll
  for (int n = 0; n < 12; n++){
    const int cc = c0 + n;
    if (cc < 64){
      const int ct = cc >> 4, lc = cc & 15, l = g2*16 + lc;
      fb[(fnp*6+ct)*512 + l*8 + half*4 + jj] = f2h(pv[n]);
    } else if (cc < 80){
      const int lc = cc - 64, l = g2*16 + lc;
      const float s = pv[n];
      const unsigned short hi = f2h(s);
      const float rem = s - (float)__builtin_bit_cast(_Float16, hi);
      fb[(fnp*6+4)*512 + l*8 + half*4 + jj] = hi;
      fb[(fnp*6+5)*512 + l*8 + half*4 + jj] = f2h(rem);
    }
  }
  if (oct == 0){
    float* b1d = reinterpret_cast<float*>((char*)strm + (size_t)e*ESTRIDE_B + 180224);
    b1d[t] = b1[e*256 + t];
  }
  if (oct == 1 && t < 80){
    float s = 0.f;
    if (t < 64){ for (int i = 0; i < 64; i++) s += b2[e*64+i]*lv[i*64+t]; }
    else       { for (int i = 0; i < 64; i++) s += b2[e*64+i]*ktlT[i*16 + (t-64)]; }
    float* bd = reinterpret_cast<float*>((char*)strm + (size_t)e*ESTRIDE_B + 181248);
    bd[t] = s;
  }
  if (blockIdx.x == 0 && t == 0) out[2097152] = -10.24032768f;
}

// ---------------------------------------------------------------------------
// main kernel: 256 blocks x 256 thr (4 waves, 1/SIMD), 1 block/CU.
// LDS (148 KB): X A-frags 64KB [0,32768) | ring s0/s1 16KB [32768,49152) |
//   Mbuf 48KB [49152,73728) (exch aliases head) | aux 2x2KB [73728,75776).
// Wave tile 64x128 (wm2 x wn2): B-frag duplication 4x -> 2x.
// All big state in AGPR-eligible accumulators; transients fit the 512-reg
// 1-wave/SIMD budget -> compiler can pipeline ds_read ahead of MFMAs.
// ---------------------------------------------------------------------------
__global__ __launch_bounds__(NTHR, 1)
void moe_main(const float* __restrict__ X, const int* __restrict__ task,
              const unsigned short* __restrict__ strm, float* __restrict__ out)
{
  __shared__ unsigned short smem[75776];   // 151,552 B
  unsigned char* exch = (unsigned char*)smem + 98304;   // aliases Mbuf head (24KB)

  const int tid  = threadIdx.x;
  const int lane = tid & 63;
  const int wid  = tid >> 6;                 // 0..3
  const int g    = lane >> 4;
  const int c    = lane & 15;
  const int wm   = wid >> 1, wn = wid & 1;   // tile 64 rows x 128 cols
  const int row0 = blockIdx.x * BM;

  auto issue16 = [&](const unsigned short* src, int sloth){   // 16KB, 4 vm/wave
    #pragma unroll
    for (int q = 0; q < 4; q++)
      gll16(src + q*2048 + tid*8, &smem[sloth + q*2048 + tid*8]);
  };
  auto issueM = [&](const unsigned short* es_, int half){     // 24KB, 6 vm/wave
    #pragma unroll
    for (int q = 0; q < 6; q++)
      gll16(es_ + 65536 + half*12288 + q*2048 + tid*8,
            &smem[49152 + half*12288 + q*2048 + tid*8]);
  };
  auto issueAux = [&](const unsigned short* es_, int k){      // 2KB, 2 vm/wave
    gll16(es_ + 90112 + lane*8, &smem[73728 + k*1024 + lane*8]);
    gll16(es_ + 90624 + lane*8, &smem[73728 + k*1024 + 512 + lane*8]);
  };

  // ---- stage X tile -> LDS in A-frag layout (once; read all 32 experts) ----
  // Xlds[(rt*8+kc)*512 + l*8 + j] = X[row0 + rt*16 + (l&15)][kc*32 + (l>>4)*8 + j]
  #pragma unroll
  for (int p = 0; p < 16; p++){
    const int id  = p*256 + tid;             // 0..4095
    const int row = id >> 5, k0 = (id & 31)*8;
    const float4 v0 = *reinterpret_cast<const float4*>(X + (size_t)(row0+row)*256 + k0);
    const float4 v1 = *reinterpret_cast<const float4*>(X + (size_t)(row0+row)*256 + k0 + 4);
    union { unsigned short s[8]; u32x4 v; } h8;
    h8.s[0]=f2h(v0.x); h8.s[1]=f2h(v0.y); h8.s[2]=f2h(v0.z); h8.s[3]=f2h(v0.w);
    h8.s[4]=f2h(v1.x); h8.s[5]=f2h(v1.y); h8.s[6]=f2h(v1.z); h8.s[7]=f2h(v1.w);
    const int l = (row & 15) | (((k0 >> 3) & 3) << 4);
    *reinterpret_cast<u32x4*>(&smem[((row>>4)*8 + (k0>>5))*512 + l*8]) = h8.v;
  }

  // tasks for OWN fm rows: fm_own = wn*2 + {0,1}; row = wm*64 + fm*16 + g*4 + j
  int tsk[2][4];
  {
    const int4 qa = *reinterpret_cast<const int4*>(&task[row0 + wm*64 + (wn*2+0)*16 + g*4]);
    const int4 qb = *reinterpret_cast<const int4*>(&task[row0 + wm*64 + (wn*2+1)*16 + g*4]);
    tsk[0][0]=qa.x; tsk[0][1]=qa.y; tsk[0][2]=qa.z; tsk[0][3]=qa.w;
    tsk[1][0]=qb.x; tsk[1][1]=qb.y; tsk[1][2]=qb.z; tsk[1][3]=qb.w;
  }

  // ring prologue: aux0, kc0 -> s0, kc1 -> s1  (FIFO: [aux:2, kc0:4, kc1:4])
  issueAux(strm, 0);
  issue16(strm,         32768);
  issue16(strm +  8192, 40960);
  LGKM0;   // X staging ds_writes drained before first barrier

  f32x4 oacc[2][4];
  float m_[2][4], d_[2][4];
  #pragma unroll
  for (int o = 0; o < 2; o++)
    #pragma unroll
    for (int j = 0; j < 4; j++){
      m_[o][j] = -1e30f; d_[o][j] = 0.f;
      #pragma unroll
      for (int ct = 0; ct < 4; ct++) oacc[o][ct][j] = 0.f;
    }
  f32x4 p[4][5];   // GEMM2 partials; filled at M(e), consumed at XFIN in kc0(e+1)

// one kc-tile: 8 B-frag + 4 A-frag reads, 32 MFMA (flat region)
#define G1STEP(SLOTH, KC) do { \
    f16x8 bf_[8], ab_[4]; \
    _Pragma("unroll") \
    for (int fnl = 0; fnl < 8; fnl++) \
      bf_[fnl] = *reinterpret_cast<const f16x8*>(&smem[(SLOTH) + (wn*8+fnl)*512 + lane*8]); \
    _Pragma("unroll") \
    for (int fmi = 0; fmi < 4; fmi++) \
      ab_[fmi] = *reinterpret_cast<const f16x8*>(&smem[((wm*4+fmi)*8 + (KC))*512 + lane*8]); \
    _Pragma("unroll") \
    for (int fnl = 0; fnl < 8; fnl++) \
      _Pragma("unroll") \
      for (int fmi = 0; fmi < 4; fmi++) \
        acc1[fnl][fmi] = __builtin_amdgcn_mfma_f32_16x16x32_f16(bf_[fnl], ab_[fmi], acc1[fnl][fmi], 0,0,0); \
  } while(0)

// GEMM2 step: 4 fm rows-blocks, static p indices
#define MSTEP(FNP) do { \
    u32x4 pr[6]; \
    _Pragma("unroll") \
    for (int i = 0; i < 6; i++) \
      pr[i] = *reinterpret_cast<const u32x4*>(&smem[49152 + wn*12288 + ((FNP)*6+i)*512 + lane*8]); \
    const f32x4 b1a = *reinterpret_cast<const f32x4*>(b1f + wn*128 + (2*(FNP)+0)*16 + g*4); \
    const f32x4 b1b = *reinterpret_cast<const f32x4*>(b1f + wn*128 + (2*(FNP)+1)*16 + g*4); \
    _Pragma("unroll") \
    for (int half = 0; half < 2; half++){ \
      const int fnl = (FNP)*2 + half; \
      const f32x4 bb = half ? b1b : b1a; \
      f16x4 a0, a1, a2, a3; \
      _Pragma("unroll") \
      for (int j = 0; j < 4; j++){ \
        a0[j] = (_Float16)fmaxf(acc1[fnl][0][j] + bb[j], 0.f); \
        a1[j] = (_Float16)fmaxf(acc1[fnl][1][j] + bb[j], 0.f); \
        a2[j] = (_Float16)fmaxf(acc1[fnl][2][j] + bb[j], 0.f); \
        a3[j] = (_Float16)fmaxf(acc1[fnl][3][j] + bb[j], 0.f); \
      } \
      _Pragma("unroll") \
      for (int ct = 0; ct < 6; ct++){ \
        union { u32x4 v; struct { f16x4 lo, hi; } h; } u; u.v = pr[ct]; \
        const f16x4 bfr = half ? u.h.hi : u.h.lo; \
        const int ci = (ct < 5) ? ct : 4; \
        p[0][ci] = __builtin_amdgcn_mfma_f32_16x16x16f16(a0, bfr, p[0][ci], 0,0,0); \
        p[1][ci] = __builtin_amdgcn_mfma_f32_16x16x16f16(a1, bfr, p[1][ci], 0,0,0); \
        p[2][ci] = __builtin_amdgcn_mfma_f32_16x16x16f16(a2, bfr, p[2][ci], 0,0,0); \
        p[3][ci] = __builtin_amdgcn_mfma_f32_16x16x16f16(a3, bfr, p[3][ci], 0,0,0); \
      } \
    } } while(0)

// write one fm partial (pv fp16 + scores f32) to exch slot
#define XW1(ACC, SLOT) do { \
    unsigned char* eb_ = exch + (SLOT)*3072; \
    _Pragma("unroll") \
    for (int ct = 0; ct < 4; ct++){ \
      union { unsigned short s[4]; u32x2 v; } p_; \
      _Pragma("unroll") \
      for (int j = 0; j < 4; j++) p_.s[j] = f2h(ACC[ct][j]); \
      *reinterpret_cast<u32x2*>(eb_ + ct*512 + lane*8) = p_.v; \
    } \
    *reinterpret_cast<f32x4*>(eb_ + 2048 + lane*16) = ACC[4]; \
  } while(0)

// finalize one own fm: own partial (f32 regs) + partner (exch) -> softmax update
#define XFIN1(ACC, SLOT, OI) do { \
    const unsigned char* eb_ = exch + (SLOT)*3072; \
    f32x4 pvv[4]; \
    _Pragma("unroll") \
    for (int ct = 0; ct < 4; ct++){ \
      union { u32x2 v; unsigned short s[4]; } pb_; \
      pb_.v = *reinterpret_cast<const u32x2*>(eb_ + ct*512 + lane*8); \
      _Pragma("unroll") \
      for (int j = 0; j < 4; j++) \
        pvv[ct][j] = ACC[ct][j] + (float)__builtin_bit_cast(_Float16, pb_.s[j]) + b2c[ct]; \
    } \
    const f32x4 s2 = *reinterpret_cast<const f32x4*>(eb_ + 2048 + lane*16); \
    _Pragma("unroll") \
    for (int j = 0; j < 4; j++){ \
      const float sv = ACC[4][j] + s2[j] + b2s; \
      const float s  = __shfl(sv, (lane & 48) | tsk[OI][j]); \
      const float mn = fmaxf(m_[OI][j], s); \
      const float al = __expf(m_[OI][j] - mn); \
      const float pe = __expf(s - mn); \
      d_[OI][j] = d_[OI][j]*al + pe; \
      m_[OI][j] = mn; \
      _Pragma("unroll") \
      for (int ct = 0; ct < 4; ct++) \
        oacc[OI][ct][j] = oacc[OI][ct][j]*al + pe*pvv[ct][j]; \
    } } while(0)

#define XFINALL(B2F) do { \
    float b2c[4]; \
    _Pragma("unroll") \
    for (int ct = 0; ct < 4; ct++) b2c[ct] = (B2F)[ct*16 + c]; \
    const float b2s = (B2F)[64 + c]; \
    if (wn == 0){ XFIN1(p[0], wm*4+0, 0); XFIN1(p[1], wm*4+1, 1); } \
    else        { XFIN1(p[2], wm*4+2, 0); XFIN1(p[3], wm*4+3, 1); } \
  } while(0)

  for (int e = 0; e < NEXP; e++){
    const unsigned short* es  = strm + (size_t)e*91136;
    const unsigned short* esn = (e == NEXP-1) ? strm : es + 91136;  // wrap: static counts
    const float* b1f = reinterpret_cast<const float*>(&smem[73728 + (e & 1)*1024]);
    f32x4 acc1[8][4] = {};

    // kc0: deferred finalize of e-1 overlaps; no issue (kc1 already in flight)
    VMW(4); BARRIER;
    G1STEP(32768, 0);
    if (e > 0){
      const float* b2p = reinterpret_cast<const float*>(&smem[73728 + ((e+1) & 1)*1024]) + 256;
      XFINALL(b2p);
    }
    // kc1..kc7: 1-ahead ring ping-pong; Mbuf at kc4/kc5; aux at kc6
    VMW(0); BARRIER; issue16(es + 2*8192, 32768);                    G1STEP(40960, 1);
    VMW(0); BARRIER; issue16(es + 3*8192, 40960);                    G1STEP(32768, 2);
    VMW(0); BARRIER; issue16(es + 4*8192, 32768);                    G1STEP(40960, 3);
    VMW(0); BARRIER; issue16(es + 5*8192, 40960); issueM(es, 0);     G1STEP(32768, 4);
    VMW(6); BARRIER; issue16(es + 6*8192, 32768); issueM(es, 1);     G1STEP(40960, 5);
    VMW(6); BARRIER; issue16(es + 7*8192, 40960); issueAux(esn, (e+1)&1); G1STEP(32768, 6);
    VMW(2); BARRIER; issue16(esn,         32768);                    G1STEP(40960, 7);

    // ---- M: GEMM2 (pv + scores) from acc1 regs; Mbuf fully landed ----
    VMW(6); BARRIER;
    issue16(esn + 8192, 40960);   // kc1' -> s1
    #pragma unroll
    for (int f = 0; f < 4; f++)
      #pragma unroll
      for (int ci = 0; ci < 5; ci++) p[f][ci] = (f32x4){0.f,0.f,0.f,0.f};
    MSTEP(0); MSTEP(1); MSTEP(2); MSTEP(3);

    // ---- X: write PARTNER fm halves to exch (aliases Mbuf; M reads done) ----
    BARRIER;
    if (wn == 0){ XW1(p[2], wm*4+2); XW1(p[3], wm*4+3); }
    else        { XW1(p[0], wm*4+0); XW1(p[1], wm*4+1); }
    LGKM0;
  }

  // ---- tail: finalize expert 31 ----
  BARRIER;
  {
    const float* b2p = reinterpret_cast<const float*>(&smem[73728 + 1*1024]) + 256;
    XFINALL(b2p);
  }
#undef XFINALL
#undef XFIN1
#undef XW1
#undef MSTEP
#undef G1STEP

  // ---- output: rows wm*64 + (wn*2+fmo)*16 + g*4 + j ----
  #pragma unroll
  for (int fmo = 0; fmo < 2; fmo++){
    #pragma unroll
    for (int j = 0; j < 4; j++){
      const float inv = 1.f / d_[fmo][j];
      float* orow = out + (size_t)(row0 + wm*64 + (wn*2+fmo)*16 + g*4 + j)*64;
      #pragma unroll
      for (int ct = 0; ct < 4; ct++)
        orow[ct*16 + c] = oacc[fmo][ct][j]*inv;
    }
  }
}

// ---------------------------------------------------------------------------
extern "C" void kernel_launch(void* const* d_in, const int* in_sizes, int n_in,
                              void* d_out, int out_size, void* d_ws, size_t ws_size,
                              hipStream_t hs)
{
  (void)in_sizes; (void)n_in; (void)out_size; (void)ws_size;
  const float* X   = (const float*)d_in[0];
  const int*   tsk = (const int*)  d_in[1];
  const float* W1  = (const float*)d_in[2];
  const float* b1  = (const float*)d_in[3];
  const float* W2  = (const float*)d_in[4];
  const float* b2  = (const float*)d_in[5];
  const float* Q   = (const float*)d_in[6];
  const float* Km  = (const float*)d_in[7];
  const float* Vm  = (const float*)d_in[8];
  float* out = (float*)d_out;

  unsigned short* strm = (unsigned short*)d_ws;

  prep_w1frag<<<dim3(256), dim3(256), 0, hs>>>(W1, strm);
  prep_wvp  <<<dim3(256), dim3(256), 0, hs>>>(W2, Vm, Km, Q, b1, b2, strm, out);
  moe_main  <<<dim3(NBLK), dim3(NTHR), 0, hs>>>(X, tsk, strm, out);
}